// Round 1
// baseline (263.543 us; speedup 1.0000x reference)
//
#include <hip/hip_runtime.h>
#include <hip/hip_bf16.h>
#include <stdint.h>
#include <stddef.h>

// Problem constants
#define BS   4096
#define NA   4
#define DD   128
#define OUTD 128
#define KI   132                 // i-dim padded 129->132 (keeps 16B alignment of h0 windows)
#define KTOT (129 * KI)          // 17028
#define KTILES 267               // ceil(17028/64)
#define BK   64
#define BM   128
#define BN   128
#define KSPLIT 4

typedef __attribute__((ext_vector_type(8))) __bf16 bf16x8;
typedef __attribute__((ext_vector_type(4))) __bf16 bf16x4;
typedef __attribute__((ext_vector_type(4))) float  f32x4;

static const size_t TB_BYTES = (size_t)NA * KTILES * 128 * 64 * 2; // 17,498,112 B

typedef const __attribute__((address_space(1))) unsigned int guint_t;
typedef __attribute__((address_space(3))) unsigned int luint_t;

__device__ __forceinline__ void async_copy16(const void* g, void* l) {
    // global -> LDS direct copy, 16B per lane; LDS dest = wave-uniform base + lane*16
    __builtin_amdgcn_global_load_lds((guint_t*)g, (luint_t*)l, 16, 0, 0);
}

// ---------------------------------------------------------------------------
// Prep: T (f32, [4][129][129][128]) -> Tb (bf16), layout per (a, ktile):
// 16KB block holding B[k][o] for k = ktile*64+kk (k=(j,i): j=k/132, i=k%132),
// stored o-major transposed: 16B unit = 8 consecutive kk of one o, at byte
// offset (o*128 + (kk/8)*16) ^ ((o&7)<<4)   [T2 swizzle baked into global data]
// ---------------------------------------------------------------------------
__global__ __launch_bounds__(256) void prep_kernel(const float* __restrict__ T,
                                                   __bf16* __restrict__ Tb) {
    int blk  = blockIdx.x;            // a*KTILES + tile
    int a    = blk / KTILES;
    int tile = blk - a * KTILES;
    int t    = threadIdx.x;
    int o    = t & 127;
    int gb   = (t >> 7) * 4;
    char* base = (char*)Tb + (size_t)blk * 16384;
    for (int g = gb; g < gb + 4; ++g) {
        bf16x8 v;
        #pragma unroll
        for (int e = 0; e < 8; ++e) {
            int kk = g * 8 + e;
            int k  = tile * 64 + kk;
            int j  = k / KI;          // h1 index
            int i  = k - j * KI;      // h0 index
            float val = 0.f;
            if (i < 129 && j < 129)
                val = T[(((size_t)a * 129 + i) * 129 + j) * 128 + o];
            v[e] = (__bf16)val;
        }
        int off = (o * 128 + g * 16) ^ ((o & 7) << 4);
        *(bf16x8*)(base + off) = v;
    }
}

// ---------------------------------------------------------------------------
// GEMM: C[b,o] += sum_k G[b,k]*Tb[a,k,o]; 128x128 tile, BK=64, 4 waves 2x2,
// double-buffered LDS, K split 4-ways, f32 atomic epilogue.
// ---------------------------------------------------------------------------
__global__ __launch_bounds__(256, 2) void gemm_kernel(const float* __restrict__ x0,
                                                      const float* __restrict__ x1,
                                                      const __bf16* __restrict__ Tb,
                                                      float* __restrict__ out) {
    __shared__ char As[2][16384];   // A tile 128 rows x 64 k, bf16, XOR-swizzled
    __shared__ char Bs[2][16384];   // B tile 128 o   x 64 k, bf16, XOR-swizzled (pre-baked)

    int bid = blockIdx.x;           // mt + 32*a + 128*ks
    int mt  = bid & 31;
    int a   = (bid >> 5) & 3;
    int ks  = bid >> 7;

    int t    = threadIdx.x;
    int lane = t & 63;
    int wid  = t >> 6;
    int wm   = wid >> 1, wn = wid & 1;

    int b0 = mt * BM;
    int t0 = ks * 67;
    int t1 = (t0 + 67 < KTILES) ? (t0 + 67) : KTILES;

    int bl = t & 127;               // staging row
    int hh = t >> 7;                // staging k-half
    const float* x0row = x0 + ((size_t)(b0 + bl) * NA + a) * DD;
    const float* x1row = x1 + ((size_t)(b0 + bl) * NA + a) * DD;
    const char*  tbb   = (const char*)Tb + (size_t)a * KTILES * 16384;

    f32x4 acc[4][4];
    #pragma unroll
    for (int i = 0; i < 4; ++i)
        #pragma unroll
        for (int j = 0; j < 4; ++j)
            acc[i][j] = (f32x4)0.f;

    auto stage = [&](int tile, int buf) {
        // ---- B: async global->LDS (data pre-swizzled in prep) ----
        {
            const char* src = tbb + (size_t)tile * 16384 + wid * 4096 + lane * 16;
            char* dst = &Bs[buf][wid * 4096];
            #pragma unroll
            for (int c = 0; c < 4; ++c)
                async_copy16(src + c * 1024, dst + c * 1024);
        }
        // ---- A: outer-product build, f32 sources, bf16 into LDS ----
        int k0t = tile * 64 + hh * 32;
        int j0  = k0t / KI;
        int i0  = k0t - j0 * KI;    // multiple of 4
        float h1v0 = (j0 < 128) ? x1row[j0] : (j0 == 128 ? 1.f : 0.f);
        int   j1   = j0 + 1;
        float h1v1 = (j1 < 128) ? x1row[j1] : (j1 == 128 ? 1.f : 0.f);
        #pragma unroll
        for (int g = 0; g < 8; ++g) {
            int iG = i0 + g * 4;
            float s = h1v0;
            if (iG >= KI) { iG -= KI; s = h1v1; }   // wave-uniform branch
            float4 h0v;
            if (iG <= 124) h0v = *(const float4*)(x0row + iG);
            else           h0v = make_float4(1.f, 0.f, 0.f, 0.f);  // iG==128 (ones col + pad)
            bf16x4 p;
            p[0] = (__bf16)(h0v.x * s);
            p[1] = (__bf16)(h0v.y * s);
            p[2] = (__bf16)(h0v.z * s);
            p[3] = (__bf16)(h0v.w * s);
            int u   = 4 * hh + (g >> 1);
            int off = bl * 128 + (((u ^ (bl & 7)) << 4) | ((g & 1) << 3));
            *(bf16x4*)(&As[buf][off]) = p;
        }
    };

    stage(t0, 0);
    __syncthreads();

    int nt = t1 - t0;
    int r16 = lane & 15;
    int kg  = lane >> 4;
    for (int tt = 0; tt < nt; ++tt) {
        int cur = tt & 1;
        if (tt + 1 < nt) stage(t0 + tt + 1, cur ^ 1);

        bf16x8 af[4][2], bfr[4][2];
        #pragma unroll
        for (int fm = 0; fm < 4; ++fm) {
            int row = wm * 64 + fm * 16 + r16;
            #pragma unroll
            for (int s = 0; s < 2; ++s) {
                int u = (4 * s + kg) ^ (r16 & 7);
                af[fm][s] = *(const bf16x8*)(&As[cur][row * 128 + u * 16]);
            }
        }
        #pragma unroll
        for (int fn = 0; fn < 4; ++fn) {
            int col = wn * 64 + fn * 16 + r16;
            #pragma unroll
            for (int s = 0; s < 2; ++s) {
                int u = (4 * s + kg) ^ (r16 & 7);
                bfr[fn][s] = *(const bf16x8*)(&Bs[cur][col * 128 + u * 16]);
            }
        }
        #pragma unroll
        for (int fm = 0; fm < 4; ++fm)
            #pragma unroll
            for (int fn = 0; fn < 4; ++fn) {
                acc[fm][fn] = __builtin_amdgcn_mfma_f32_16x16x32_bf16(af[fm][0], bfr[fn][0], acc[fm][fn], 0, 0, 0);
                acc[fm][fn] = __builtin_amdgcn_mfma_f32_16x16x32_bf16(af[fm][1], bfr[fn][1], acc[fm][fn], 0, 0, 0);
            }
        __syncthreads();
    }

    // Epilogue: C/D layout col=lane&15, row=(lane>>4)*4+r (verified mapping)
    #pragma unroll
    for (int fm = 0; fm < 4; ++fm)
        #pragma unroll
        for (int fn = 0; fn < 4; ++fn)
            #pragma unroll
            for (int r = 0; r < 4; ++r) {
                int row = b0 + wm * 64 + fm * 16 + (lane >> 4) * 4 + r;
                int col = wn * 64 + fn * 16 + (lane & 15);
                unsafeAtomicAdd(&out[((size_t)row * NA + a) * OUTD + col], acc[fm][fn][r]);
            }
}

// ---------------------------------------------------------------------------
// Fallback (ws too small): naive but correct f32 kernel.
// ---------------------------------------------------------------------------
__global__ __launch_bounds__(128) void fallback_kernel(const float* __restrict__ x0,
                                                       const float* __restrict__ x1,
                                                       const float* __restrict__ T,
                                                       float* __restrict__ out) {
    int ba = blockIdx.x;
    int b = ba >> 2, a = ba & 3;
    int o = threadIdx.x;
    const float* h0 = x0 + ((size_t)b * NA + a) * DD;
    const float* h1 = x1 + ((size_t)b * NA + a) * DD;
    float acc = 0.f;
    for (int i = 0; i < 129; ++i) {
        float h0i = (i < 128) ? h0[i] : 1.f;
        const float* Trow = T + (((size_t)a * 129 + i) * 129) * 128 + o;
        float part = 0.f;
        for (int j = 0; j < 129; ++j) {
            float h1j = (j < 128) ? h1[j] : 1.f;
            part += h1j * Trow[(size_t)j * 128];
        }
        acc += h0i * part;
    }
    out[((size_t)b * NA + a) * OUTD + o] = acc;
}

extern "C" void kernel_launch(void* const* d_in, const int* in_sizes, int n_in,
                              void* d_out, int out_size, void* d_ws, size_t ws_size,
                              hipStream_t stream) {
    const float* x0 = (const float*)d_in[0];
    const float* x1 = (const float*)d_in[1];
    const float* T  = (const float*)d_in[2];
    float* out = (float*)d_out;

    if (ws_size < TB_BYTES) {
        // not enough scratch for the bf16-repacked T: slow-but-correct path
        fallback_kernel<<<BS * NA, 128, 0, stream>>>(x0, x1, T, out);
        return;
    }

    __bf16* Tb = (__bf16*)d_ws;
    hipMemsetAsync(d_out, 0, (size_t)out_size * sizeof(float), stream);
    prep_kernel<<<NA * KTILES, 256, 0, stream>>>(T, Tb);
    gemm_kernel<<<32 * NA * KSPLIT, 256, 0, stream>>>(x0, x1, Tb, out);
}

// Round 2
// 124.519 us; speedup vs baseline: 2.1165x; 2.1165x over previous
//
#include <hip/hip_runtime.h>
#include <stdint.h>
#include <stddef.h>

// Problem constants
#define NA     4
#define DD     128
#define OUTD   128
#define BK     32
#define BM     128
#define BN     128
#define KTILES 521            // 512 main (k=j*128+i, i,j<128) + 4 h1-corr + 4 h0-corr + 1 const
#define KSPLIT 4
#define TILE_BYTES 8192       // BN * BK * 2B

typedef _Float16 f16;
typedef __attribute__((ext_vector_type(8))) _Float16 f16x8;
typedef __attribute__((ext_vector_type(4))) float   f32x4;

static const size_t TB_BYTES = (size_t)NA * KTILES * TILE_BYTES; // ~17.07 MB

typedef const __attribute__((address_space(1))) unsigned int guint_t;
typedef __attribute__((address_space(3))) unsigned int luint_t;

__device__ __forceinline__ void async_copy16(const void* g, void* l) {
    // global -> LDS direct, 16B/lane; LDS dest = wave-uniform base + lane*16
    __builtin_amdgcn_global_load_lds((guint_t*)g, (luint_t*)l, 16, 0, 0);
}

// ---------------------------------------------------------------------------
// Prep: T f32 [4][129][129][128] -> Tb f16, per (a,tile) an 8KB image, unit
// v = w*128 + col (w = k-window 0..3) holds elements k=tile*32+w*8+e at col.
// K map: k<16384: (i=k&127, j=k>>7); 16384..16511: i=128 row (h1 terms);
// 16512..16639: j=128 col (h0 terms); 16640: T[128][128]; rest zero.
// Window-major layout is bank-conflict-free for the fragment reads and is
// written linearly by global_load_lds (no swizzle needed).
// ---------------------------------------------------------------------------
__global__ __launch_bounds__(256) void prep_kernel(const float* __restrict__ T,
                                                   f16* __restrict__ Tb) {
    int blk  = blockIdx.x;            // a*KTILES + tile
    int a    = blk / KTILES;
    int tile = blk - a * KTILES;
    int t    = threadIdx.x;
    f16* base = Tb + (size_t)blk * (TILE_BYTES / 2);
    #pragma unroll
    for (int h = 0; h < 2; ++h) {
        int v   = t + h * 256;        // unit 0..511
        int w   = v >> 7;
        int col = v & 127;
        f16x8 outv;
        #pragma unroll
        for (int e = 0; e < 8; ++e) {
            int k = tile * 32 + w * 8 + e;
            int i = -1, j = 0;
            if (k < 16384)       { i = k & 127;   j = k >> 7;    }
            else if (k < 16512)  { i = 128;       j = k - 16384; }
            else if (k < 16640)  { i = k - 16512; j = 128;       }
            else if (k == 16640) { i = 128;       j = 128;       }
            float val = 0.f;
            if (i >= 0) val = T[(((size_t)a * 129 + i) * 129 + j) * 128 + col];
            outv[e] = (f16)val;
        }
        *(f16x8*)(base + (size_t)v * 8) = outv;
    }
}

// ---------------------------------------------------------------------------
// GEMM: C[b,o] += sum_k G[b,k] * Tb[a,k,o], G = h0*h1 (register-built A).
// BM=128 x BN=128, BK=32, 4 waves of 64x64, 2 blocks/CU (80KiB LDS each).
// ---------------------------------------------------------------------------
__global__ __launch_bounds__(256, 2) void gemm_kernel(const float* __restrict__ x0,
                                                      const float* __restrict__ x1,
                                                      const f16* __restrict__ Tb,
                                                      float* __restrict__ out) {
    __shared__ f16 h0img[16384];     // 32KB: unit (u*128+row)*8 holds h0[row][u*8..+7]
    __shared__ f16 h1t[16384];       // 32KB: h1t[j*128+row] = h1[row][j]
    __shared__ char Bs[2][TILE_BYTES]; // 16KB double-buffered B tile

    int bid = blockIdx.x;
    int wg  = (bid & 7) * 64 + (bid >> 3);   // XCD-contiguous swizzle (512 = 8*64)
    int mt  = wg & 31;
    int a   = (wg >> 5) & 3;
    int ks  = wg >> 7;

    int t    = threadIdx.x;
    int lane = t & 63;
    int wid  = t >> 6;
    int wm   = wid >> 1, wn = wid & 1;
    int r16  = lane & 15, kg = lane >> 4;

    int b0 = mt * BM;
    int t0 = ks * 131;
    int t1 = (t0 + 131 < KTILES) ? t0 + 131 : KTILES;
    int nt = t1 - t0;

    const char* tbb = (const char*)Tb + (size_t)a * KTILES * TILE_BYTES;

    auto stage = [&](int tile, int buf) {
        const char* src = tbb + (size_t)tile * TILE_BYTES + wid * 2048 + lane * 16;
        char* dst = &Bs[buf][wid * 2048];
        async_copy16(src,        dst);
        async_copy16(src + 1024, dst + 1024);
    };

    stage(t0, 0);   // overlap first B-stage with x setup

    // ---- one-time x0/x1 -> LDS (f16) ----
    {
        int row  = t & 127;
        int half = t >> 7;
        const float* x0row = x0 + ((size_t)(b0 + row) * NA + a) * DD;
        const float* x1row = x1 + ((size_t)(b0 + row) * NA + a) * DD;
        #pragma unroll
        for (int q = 0; q < 8; ++q) {
            int u = half * 8 + q;
            f32x4 v0 = *(const f32x4*)(x0row + u * 8);
            f32x4 v1 = *(const f32x4*)(x0row + u * 8 + 4);
            f16x8 w;
            #pragma unroll
            for (int e = 0; e < 4; ++e) { w[e] = (f16)v0[e]; w[e + 4] = (f16)v1[e]; }
            *(f16x8*)(&h0img[(u * 128 + row) * 8]) = w;
            f32x4 y0 = *(const f32x4*)(x1row + u * 8);
            f32x4 y1 = *(const f32x4*)(x1row + u * 8 + 4);
            #pragma unroll
            for (int e = 0; e < 4; ++e) {
                h1t[(u * 8 + e) * 128 + row]     = (f16)y0[e];
                h1t[(u * 8 + e + 4) * 128 + row] = (f16)y1[e];
            }
        }
    }
    __syncthreads();

    f32x4 acc[4][4];
    #pragma unroll
    for (int i = 0; i < 4; ++i)
        #pragma unroll
        for (int j = 0; j < 4; ++j) acc[i][j] = (f32x4)0.f;

    f16 h1v[4] = {(f16)0.f, (f16)0.f, (f16)0.f, (f16)0.f};

    for (int tt = 0; tt < nt; ++tt) {
        int cur  = tt & 1;
        int tile = t0 + tt;
        if (tt + 1 < nt) stage(tile + 1, cur ^ 1);

        // per-row h1[j] scalars (j = tile>>2, tile-uniform; reload every 4 tiles)
        if ((tt == 0 || (tile & 3) == 0) && tile < 512) {
            int j = tile >> 2;
            #pragma unroll
            for (int fm = 0; fm < 4; ++fm)
                h1v[fm] = h1t[j * 128 + (wm * 64 + fm * 16 + r16)];
        }

        // ---- A fragments in registers ----
        f16x8 af[4];
        if (tile < 512) {
            int u0 = (tile & 3) * 4 + kg;
            #pragma unroll
            for (int fm = 0; fm < 4; ++fm) {
                int row = wm * 64 + fm * 16 + r16;
                f16x8 h0w = *(const f16x8*)(&h0img[(u0 * 128 + row) * 8]);
                af[fm] = h0w * h1v[fm];
            }
        } else if (tile < 516) {           // G = h1[j], j = k-16384
            int jb = (tile - 512) * 32 + kg * 8;
            #pragma unroll
            for (int fm = 0; fm < 4; ++fm) {
                int row = wm * 64 + fm * 16 + r16;
                f16x8 w;
                #pragma unroll
                for (int e = 0; e < 8; ++e) w[e] = h1t[(jb + e) * 128 + row];
                af[fm] = w;
            }
        } else if (tile < 520) {           // G = h0[i], i = k-16512
            int u0 = (tile - 516) * 4 + kg;
            #pragma unroll
            for (int fm = 0; fm < 4; ++fm) {
                int row = wm * 64 + fm * 16 + r16;
                af[fm] = *(const f16x8*)(&h0img[(u0 * 128 + row) * 8]);
            }
        } else {                           // k=16640: G = 1 at first elem
            f16x8 w;
            #pragma unroll
            for (int e = 0; e < 8; ++e) w[e] = (f16)0.f;
            if (kg == 0) w[0] = (f16)1.f;
            #pragma unroll
            for (int fm = 0; fm < 4; ++fm) af[fm] = w;
        }

        // ---- B fragments from LDS (window-major, conflict-free) ----
        f16x8 bfr[4];
        #pragma unroll
        for (int fn = 0; fn < 4; ++fn) {
            int col = wn * 64 + fn * 16 + r16;
            bfr[fn] = *(const f16x8*)(&Bs[cur][(kg * 128 + col) * 16]);
        }

        #pragma unroll
        for (int fm = 0; fm < 4; ++fm)
            #pragma unroll
            for (int fn = 0; fn < 4; ++fn)
                acc[fm][fn] = __builtin_amdgcn_mfma_f32_16x16x32_f16(af[fm], bfr[fn], acc[fm][fn], 0, 0, 0);

        __syncthreads();
    }

    // Epilogue: C/D layout col=lane&15, row=(lane>>4)*4+r (verified)
    #pragma unroll
    for (int fm = 0; fm < 4; ++fm)
        #pragma unroll
        for (int fn = 0; fn < 4; ++fn)
            #pragma unroll
            for (int r = 0; r < 4; ++r) {
                int row = b0 + wm * 64 + fm * 16 + (lane >> 4) * 4 + r;
                int col = wn * 64 + fn * 16 + (lane & 15);
                unsafeAtomicAdd(&out[((size_t)row * NA + a) * OUTD + col], acc[fm][fn][r]);
            }
}

// ---------------------------------------------------------------------------
// Fallback (ws too small): naive but correct f32 kernel.
// ---------------------------------------------------------------------------
__global__ __launch_bounds__(128) void fallback_kernel(const float* __restrict__ x0,
                                                       const float* __restrict__ x1,
                                                       const float* __restrict__ T,
                                                       float* __restrict__ out) {
    int ba = blockIdx.x;
    int b = ba >> 2, a = ba & 3;
    int o = threadIdx.x;
    const float* h0 = x0 + ((size_t)b * NA + a) * DD;
    const float* h1 = x1 + ((size_t)b * NA + a) * DD;
    float acc = 0.f;
    for (int i = 0; i < 129; ++i) {
        float h0i = (i < 128) ? h0[i] : 1.f;
        const float* Trow = T + (((size_t)a * 129 + i) * 129) * 128 + o;
        float part = 0.f;
        for (int j = 0; j < 129; ++j) {
            float h1j = (j < 128) ? h1[j] : 1.f;
            part += h1j * Trow[(size_t)j * 128];
        }
        acc += h0i * part;
    }
    out[((size_t)b * NA + a) * OUTD + o] = acc;
}

extern "C" void kernel_launch(void* const* d_in, const int* in_sizes, int n_in,
                              void* d_out, int out_size, void* d_ws, size_t ws_size,
                              hipStream_t stream) {
    const float* x0 = (const float*)d_in[0];
    const float* x1 = (const float*)d_in[1];
    const float* T  = (const float*)d_in[2];
    float* out = (float*)d_out;

    if (ws_size < TB_BYTES) {
        fallback_kernel<<<4096 * NA, 128, 0, stream>>>(x0, x1, T, out);
        return;
    }

    f16* Tb = (f16*)d_ws;
    hipMemsetAsync(d_out, 0, (size_t)out_size * sizeof(float), stream);
    prep_kernel<<<NA * KTILES, 256, 0, stream>>>(T, Tb);
    gemm_kernel<<<32 * NA * KSPLIT, 256, 0, stream>>>(x0, x1, Tb, out);
}

// Round 3
// 122.639 us; speedup vs baseline: 2.1489x; 1.0153x over previous
//
#include <hip/hip_runtime.h>
#include <stdint.h>
#include <stddef.h>

// Problem: out[b,a,o] = sum_{i,j} h0[b,a,i] h1[b,a,j] T[a,i,j,o], h=concat(x,1)
// GEMM form: C[b,o] += G[b,k]*Tb[a,k,o]; main k=j*128+i (i,j<128), k=16384+c:
// G=h1[c]; k=16512+c: G=h0[c]; k=16640: G=1. 261 K-tiles of 64.
#define NA     4
#define DDIM   128
#define OUTD   128
#define BM     256
#define BN     128
#define NTILES 261
#define TILE_B 16384          // BN * 64 * 2B

typedef _Float16 f16;
typedef __attribute__((ext_vector_type(8)))  _Float16 f16x8;
typedef __attribute__((ext_vector_type(4)))  float    f32x4;
typedef __attribute__((ext_vector_type(16))) float    f32x16;

static const size_t TB_BYTES = (size_t)NA * NTILES * TILE_B;   // 17,104,896

typedef const __attribute__((address_space(1))) unsigned int guint_t;
typedef __attribute__((address_space(3))) unsigned int luint_t;

__device__ __forceinline__ void async_copy16(const void* g, void* l) {
    // global -> LDS direct, 16B/lane; LDS dest = wave-uniform base + lane*16
    __builtin_amdgcn_global_load_lds((guint_t*)g, (luint_t*)l, 16, 0, 0);
}

// ---------------------------------------------------------------------------
// Prep: T f32 -> Tb f16, per (a,tile) a 16KB image; unit v = w*128+col
// (w=0..7) holds k = tile*64 + w*8 + e at output-col `col`.
// ---------------------------------------------------------------------------
__global__ __launch_bounds__(256) void prep_kernel(const float* __restrict__ T,
                                                   f16* __restrict__ Tb) {
    int blk  = blockIdx.x;            // a*NTILES + tile
    int a    = blk / NTILES;
    int tile = blk - a * NTILES;
    int t    = threadIdx.x;
    f16* base = Tb + (size_t)blk * (TILE_B / 2);
    #pragma unroll
    for (int u = 0; u < 4; ++u) {
        int v   = t + u * 256;
        int w   = v >> 7;
        int col = v & 127;
        f16x8 ov;
        #pragma unroll
        for (int e = 0; e < 8; ++e) {
            int k = tile * 64 + w * 8 + e;
            int i = -1, j = 0;
            if (k < 16384)       { i = k & 127;   j = k >> 7;    }
            else if (k < 16512)  { i = 128;       j = k - 16384; }
            else if (k < 16640)  { i = k - 16512; j = 128;       }
            else if (k == 16640) { i = 128;       j = 128;       }
            float val = 0.f;
            if (i >= 0) val = T[(((size_t)a * 129 + i) * 129 + j) * 128 + col];
            ov[e] = (f16)val;
        }
        *(f16x8*)(base + (size_t)v * 8) = ov;
    }
}

// ---------------------------------------------------------------------------
// GEMM: BM=256 x BN=128, BK=64, 8 waves (4M x 2N), per-wave 64x64 via
// mfma_f32_32x32x16_f16. A built in registers (h0 stationary, h1 scalar).
// 3-buffer B pipeline, counted vmcnt(2), one barrier/iter.
// ---------------------------------------------------------------------------
__global__ __launch_bounds__(512, 2) void gemm_kernel(const float* __restrict__ x0,
                                                      const float* __restrict__ x1,
                                                      const f16* __restrict__ Tb,
                                                      float* __restrict__ out) {
    __shared__ f16  h1t[128 * 256];   // 64KB: h1t[j*256+row] = x1[b0+row][a][j]
    __shared__ char Bs[3][TILE_B];    // 48KB: B tile triple buffer

    int bid  = blockIdx.x;
    int xcd  = bid & 7, idx = bid >> 3;
    int pair = xcd * 2 + (idx >> 4);  // same (a,ks) pairs contiguous per XCD
    int mt   = idx & 15;
    int a    = pair & 3;
    int ks   = pair >> 2;

    int t    = threadIdx.x;
    int lane = t & 63, wid = t >> 6;
    int wm   = wid >> 1, wn = wid & 1;
    int l31  = lane & 31, hi = lane >> 5;
    int b0   = mt * BM;

    const char* tbb = (const char*)Tb + (size_t)a * NTILES * TILE_B;
    int nt = (ks == 0) ? 66 : 65;     // 64 main tiles + correction tail

    auto tile_at = [&](int tt) -> int {
        if (tt < 64) return ks * 64 + tt;
        if (ks == 0) return (tt == 64) ? 256 : 260;
        return 256 + ks;              // ks1->257(j-corr hi), ks2->258, ks3->259
    };
    auto stage = [&](int tt, int buf) {
        const char* src = tbb + (size_t)tile_at(tt) * TILE_B + wid * 2048 + lane * 16;
        char* dst = &Bs[buf][wid * 2048];
        async_copy16(src,        dst);
        async_copy16(src + 1024, dst + 1024);
    };

    // prologue: prefetch tiles 0,1
    stage(0, 0);
    stage(1, 1);

    // ---- one-time h1 -> LDS (transposed, f16) ----
    {
        int row = t & 255, hs = t >> 8;
        const float* x1r = x1 + ((size_t)(b0 + row) * NA + a) * DDIM + hs * 64;
        #pragma unroll
        for (int q = 0; q < 16; ++q) {
            f32x4 v = *(const f32x4*)(x1r + q * 4);
            #pragma unroll
            for (int e = 0; e < 4; ++e)
                h1t[(hs * 64 + q * 4 + e) * 256 + row] = (f16)v[e];
        }
    }
    // ---- one-time h0 -> registers (per-lane stationary windows) ----
    f16x8 h0reg[2][8];                // [fm][t]: window 2t+hi of row fm
    #pragma unroll
    for (int fm = 0; fm < 2; ++fm) {
        int row = b0 + wm * 64 + fm * 32 + l31;
        const float* x0r = x0 + ((size_t)row * NA + a) * DDIM;
        #pragma unroll
        for (int w = 0; w < 8; ++w) {
            int wf = 2 * w + hi;
            f32x4 v0 = *(const f32x4*)(x0r + wf * 8);
            f32x4 v1 = *(const f32x4*)(x0r + wf * 8 + 4);
            f16x8 h;
            #pragma unroll
            for (int e = 0; e < 4; ++e) { h[e] = (f16)v0[e]; h[e + 4] = (f16)v1[e]; }
            h0reg[fm][w] = h;
        }
    }
    __syncthreads();

    f32x16 acc[2][2];
    #pragma unroll
    for (int i = 0; i < 2; ++i)
        #pragma unroll
        for (int j = 0; j < 2; ++j) acc[i][j] = (f32x16)0.f;

    // ---- main loop: 64 tiles, unrolled x2 so register indices are static ----
    for (int p = 0; p < 32; ++p) {
        int j = ks * 32 + p;          // j = tile>>1, same for both halves
        f16 h1v[2];
        h1v[0] = h1t[j * 256 + (wm * 64 + l31)];
        h1v[1] = h1t[j * 256 + (wm * 64 + 32 + l31)];
        #pragma unroll
        for (int par = 0; par < 2; ++par) {
            int tt = 2 * p + par;
            asm volatile("s_waitcnt vmcnt(2)" ::: "memory");
            __syncthreads();
            if (tt + 2 < nt) stage(tt + 2, (tt + 2) % 3);
            const char* bb = Bs[tt % 3];
            __builtin_amdgcn_s_setprio(1);
            #pragma unroll
            for (int kk = 0; kk < 4; ++kk) {
                f16x8 bf0 = *(const f16x8*)(bb + ((kk * 2 + hi) * 128 + wn * 64 + l31) * 16);
                f16x8 bf1 = *(const f16x8*)(bb + ((kk * 2 + hi) * 128 + wn * 64 + 32 + l31) * 16);
                f16x8 a0 = h0reg[0][par * 4 + kk] * h1v[0];
                f16x8 a1 = h0reg[1][par * 4 + kk] * h1v[1];
                acc[0][0] = __builtin_amdgcn_mfma_f32_32x32x16_f16(a0, bf0, acc[0][0], 0, 0, 0);
                acc[0][1] = __builtin_amdgcn_mfma_f32_32x32x16_f16(a0, bf1, acc[0][1], 0, 0, 0);
                acc[1][0] = __builtin_amdgcn_mfma_f32_32x32x16_f16(a1, bf0, acc[1][0], 0, 0, 0);
                acc[1][1] = __builtin_amdgcn_mfma_f32_32x32x16_f16(a1, bf1, acc[1][1], 0, 0, 0);
            }
            __builtin_amdgcn_s_setprio(0);
        }
    }

    // ---- correction tail (1-2 tiles) ----
    for (int tt = 64; tt < nt; ++tt) {
        int tile = tile_at(tt);
        if (tt + 1 < nt) asm volatile("s_waitcnt vmcnt(2)" ::: "memory");
        else             asm volatile("s_waitcnt vmcnt(0)" ::: "memory");
        __syncthreads();
        if (tt + 2 < nt) stage(tt + 2, (tt + 2) % 3);
        const char* bb = Bs[tt % 3];

        f16x8 af[2][4];
        if (tile < 258) {                       // j-corr: G = h1[c]
            int jb = (tile - 256) * 64;
            #pragma unroll
            for (int fm = 0; fm < 2; ++fm) {
                int row = wm * 64 + fm * 32 + l31;
                #pragma unroll
                for (int kk = 0; kk < 4; ++kk) {
                    f16x8 w;
                    #pragma unroll
                    for (int e = 0; e < 8; ++e)
                        w[e] = h1t[(jb + kk * 16 + hi * 8 + e) * 256 + row];
                    af[fm][kk] = w;
                }
            }
        } else if (tile == 258) {               // i-corr lo: G = h0[c], c<64
            #pragma unroll
            for (int fm = 0; fm < 2; ++fm)
                #pragma unroll
                for (int kk = 0; kk < 4; ++kk) af[fm][kk] = h0reg[fm][kk];
        } else if (tile == 259) {               // i-corr hi: c in [64,128)
            #pragma unroll
            for (int fm = 0; fm < 2; ++fm)
                #pragma unroll
                for (int kk = 0; kk < 4; ++kk) af[fm][kk] = h0reg[fm][4 + kk];
        } else {                                // tile 260: G = 1 at k_local 0
            f16x8 z = (f16x8)(f16)0.f;
            f16x8 o = z;
            if (hi == 0) o[0] = (f16)1.f;
            #pragma unroll
            for (int fm = 0; fm < 2; ++fm) {
                af[fm][0] = o;
                af[fm][1] = z; af[fm][2] = z; af[fm][3] = z;
            }
        }

        __builtin_amdgcn_s_setprio(1);
        #pragma unroll
        for (int kk = 0; kk < 4; ++kk) {
            f16x8 bf0 = *(const f16x8*)(bb + ((kk * 2 + hi) * 128 + wn * 64 + l31) * 16);
            f16x8 bf1 = *(const f16x8*)(bb + ((kk * 2 + hi) * 128 + wn * 64 + 32 + l31) * 16);
            acc[0][0] = __builtin_amdgcn_mfma_f32_32x32x16_f16(af[0][kk], bf0, acc[0][0], 0, 0, 0);
            acc[0][1] = __builtin_amdgcn_mfma_f32_32x32x16_f16(af[0][kk], bf1, acc[0][1], 0, 0, 0);
            acc[1][0] = __builtin_amdgcn_mfma_f32_32x32x16_f16(af[1][kk], bf0, acc[1][0], 0, 0, 0);
            acc[1][1] = __builtin_amdgcn_mfma_f32_32x32x16_f16(af[1][kk], bf1, acc[1][1], 0, 0, 0);
        }
        __builtin_amdgcn_s_setprio(0);
    }

    // ---- epilogue: 32x32 C/D layout col=lane&31, row=(r&3)+8*(r>>2)+4*hi ----
    #pragma unroll
    for (int fm = 0; fm < 2; ++fm)
        #pragma unroll
        for (int fn = 0; fn < 2; ++fn)
            #pragma unroll
            for (int r = 0; r < 16; ++r) {
                int row = b0 + wm * 64 + fm * 32 + (r & 3) + 8 * (r >> 2) + 4 * hi;
                int col = wn * 64 + fn * 32 + l31;
                unsafeAtomicAdd(&out[((size_t)row * NA + a) * OUTD + col], acc[fm][fn][r]);
            }
}

// ---------------------------------------------------------------------------
// Fallback (ws too small): naive but correct f32 kernel.
// ---------------------------------------------------------------------------
__global__ __launch_bounds__(128) void fallback_kernel(const float* __restrict__ x0,
                                                       const float* __restrict__ x1,
                                                       const float* __restrict__ T,
                                                       float* __restrict__ out) {
    int ba = blockIdx.x;
    int b = ba >> 2, a = ba & 3;
    int o = threadIdx.x;
    const float* h0 = x0 + ((size_t)b * NA + a) * DDIM;
    const float* h1 = x1 + ((size_t)b * NA + a) * DDIM;
    float acc = 0.f;
    for (int i = 0; i < 129; ++i) {
        float h0i = (i < 128) ? h0[i] : 1.f;
        const float* Trow = T + (((size_t)a * 129 + i) * 129) * 128 + o;
        float part = 0.f;
        for (int j = 0; j < 129; ++j) {
            float h1j = (j < 128) ? h1[j] : 1.f;
            part += h1j * Trow[(size_t)j * 128];
        }
        acc += h0i * part;
    }
    out[((size_t)b * NA + a) * OUTD + o] = acc;
}

extern "C" void kernel_launch(void* const* d_in, const int* in_sizes, int n_in,
                              void* d_out, int out_size, void* d_ws, size_t ws_size,
                              hipStream_t stream) {
    const float* x0 = (const float*)d_in[0];
    const float* x1 = (const float*)d_in[1];
    const float* T  = (const float*)d_in[2];
    float* out = (float*)d_out;

    if (ws_size < TB_BYTES) {
        fallback_kernel<<<4096 * NA, 128, 0, stream>>>(x0, x1, T, out);
        return;
    }

    f16* Tb = (f16*)d_ws;
    hipMemsetAsync(d_out, 0, (size_t)out_size * sizeof(float), stream);
    prep_kernel<<<NA * NTILES, 256, 0, stream>>>(T, Tb);
    gemm_kernel<<<256, 512, 0, stream>>>(x0, x1, Tb, out);
}

// Round 4
// 105.402 us; speedup vs baseline: 2.5004x; 1.1635x over previous
//
#include <hip/hip_runtime.h>
#include <stdint.h>
#include <stddef.h>

// Problem: out[b,a,o] = sum_{i,j} h0[b,a,i] h1[b,a,j] T[a,i,j,o], h=concat(x,1)
// GEMM form: C[b,o] += G[b,k]*Tb[a,k,o]; main k=j*128+i (i,j<128); k=16384+c:
// G=h1[c]; k=16512+c: G=h0[c]; k=16640: G=1. 261 K-tiles of 64.
#define NA     4
#define DDIM   128
#define OUTD   128
#define BM     256
#define BN     128
#define NTILES 261
#define TILE_B 16384          // BN * 64 * 2B
#define OUT_ELEMS (4096 * NA * OUTD)   // 2,097,152 f32

typedef _Float16 f16;
typedef __attribute__((ext_vector_type(8)))  _Float16 f16x8;
typedef __attribute__((ext_vector_type(4)))  float    f32x4;
typedef __attribute__((ext_vector_type(16))) float    f32x16;

static const size_t TB_BYTES  = (size_t)NA * NTILES * TILE_B;        // 17,104,896
static const size_t P_BYTES   = (size_t)4 * OUT_ELEMS * sizeof(float); // 33,554,432
static const size_t WS_NEEDED = TB_BYTES + P_BYTES;                  // ~50.7 MB

typedef const __attribute__((address_space(1))) unsigned int guint_t;
typedef __attribute__((address_space(3))) unsigned int luint_t;

__device__ __forceinline__ void async_copy16(const void* g, void* l) {
    __builtin_amdgcn_global_load_lds((guint_t*)g, (luint_t*)l, 16, 0, 0);
}

// ---------------------------------------------------------------------------
// Prep: T f32 -> Tb f16, per (a,tile) a 16KB image; unit v = w*128+col
// (w=0..7) holds k = tile*64 + w*8 + e at output-col `col`.
// ---------------------------------------------------------------------------
__global__ __launch_bounds__(256) void prep_kernel(const float* __restrict__ T,
                                                   f16* __restrict__ Tb) {
    int blk  = blockIdx.x;            // a*NTILES + tile
    int a    = blk / NTILES;
    int tile = blk - a * NTILES;
    int t    = threadIdx.x;
    f16* base = Tb + (size_t)blk * (TILE_B / 2);
    #pragma unroll
    for (int u = 0; u < 4; ++u) {
        int v   = t + u * 256;
        int w   = v >> 7;
        int col = v & 127;
        f16x8 ov;
        #pragma unroll
        for (int e = 0; e < 8; ++e) {
            int k = tile * 64 + w * 8 + e;
            int i = -1, j = 0;
            if (k < 16384)       { i = k & 127;   j = k >> 7;    }
            else if (k < 16512)  { i = 128;       j = k - 16384; }
            else if (k < 16640)  { i = k - 16512; j = 128;       }
            else if (k == 16640) { i = 128;       j = 128;       }
            float val = 0.f;
            if (i >= 0) val = T[(((size_t)a * 129 + i) * 129 + j) * 128 + col];
            ov[e] = (f16)val;
        }
        *(f16x8*)(base + (size_t)v * 8) = ov;
    }
}

// ---------------------------------------------------------------------------
// GEMM: BM=256 x BN=128, BK=64, 8 waves (4M x 2N), per-wave 64x64 via
// mfma_f32_32x32x16_f16. A in registers; raw s_barrier + counted vmcnt(2);
// epilogue: plain stores to per-ks partials (ATOMIC=false) or atomics.
// ---------------------------------------------------------------------------
template <bool ATOMIC>
__global__ __launch_bounds__(512, 2) void gemm_kernel(const float* __restrict__ x0,
                                                      const float* __restrict__ x1,
                                                      const f16* __restrict__ Tb,
                                                      float* __restrict__ dst) {
    __shared__ __align__(16) f16  h1t[128 * 256];   // 64KB
    __shared__ __align__(16) char Bs[3][TILE_B];    // 48KB triple buffer

    int bid  = blockIdx.x;
    int xcd  = bid & 7, idx = bid >> 3;
    int pair = xcd * 2 + (idx >> 4);  // (a,ks) pairs contiguous per XCD
    int mt   = idx & 15;
    int a    = pair & 3;
    int ks   = pair >> 2;

    int t    = threadIdx.x;
    int lane = t & 63, wid = t >> 6;
    int wm   = wid >> 1, wn = wid & 1;
    int l31  = lane & 31, hi = lane >> 5;
    int b0   = mt * BM;

    const char* tbb = (const char*)Tb + (size_t)a * NTILES * TILE_B;
    int nt = (ks == 0) ? 66 : 65;

    auto tile_at = [&](int tt) -> int {
        if (tt < 64) return ks * 64 + tt;
        if (ks == 0) return (tt == 64) ? 256 : 260;
        return 256 + ks;
    };
    auto stage = [&](int tt, int buf) {
        const char* src = tbb + (size_t)tile_at(tt) * TILE_B + wid * 2048 + lane * 16;
        char* dstl = &Bs[buf][wid * 2048];
        async_copy16(src,        dstl);
        async_copy16(src + 1024, dstl + 1024);
    };

    stage(0, 0);
    stage(1, 1);

    // ---- one-time h1 -> LDS (transposed, f16) ----
    {
        int row = t & 255, hs = t >> 8;
        const float* x1r = x1 + ((size_t)(b0 + row) * NA + a) * DDIM + hs * 64;
        #pragma unroll
        for (int q = 0; q < 16; ++q) {
            f32x4 v = *(const f32x4*)(x1r + q * 4);
            #pragma unroll
            for (int e = 0; e < 4; ++e)
                h1t[(hs * 64 + q * 4 + e) * 256 + row] = (f16)v[e];
        }
    }
    // ---- one-time h0 -> registers ----
    f16x8 h0reg[2][8];
    #pragma unroll
    for (int fm = 0; fm < 2; ++fm) {
        int row = b0 + wm * 64 + fm * 32 + l31;
        const float* x0r = x0 + ((size_t)row * NA + a) * DDIM;
        #pragma unroll
        for (int w = 0; w < 8; ++w) {
            int wf = 2 * w + hi;
            f32x4 v0 = *(const f32x4*)(x0r + wf * 8);
            f32x4 v1 = *(const f32x4*)(x0r + wf * 8 + 4);
            f16x8 h;
            #pragma unroll
            for (int e = 0; e < 4; ++e) { h[e] = (f16)v0[e]; h[e + 4] = (f16)v1[e]; }
            h0reg[fm][w] = h;
        }
    }
    __syncthreads();   // full drain once: h1t visible to all

    f32x16 acc[2][2];
    #pragma unroll
    for (int i = 0; i < 2; ++i)
        #pragma unroll
        for (int j = 0; j < 2; ++j) acc[i][j] = (f32x16)0.f;

    // ---- main loop: 64 tiles; raw barrier, counted vmcnt(2), never drained ----
    for (int p = 0; p < 32; ++p) {
        int j = ks * 32 + p;
        f16 h1v[2];
        h1v[0] = h1t[j * 256 + (wm * 64 + l31)];
        h1v[1] = h1t[j * 256 + (wm * 64 + 32 + l31)];
        #pragma unroll
        for (int par = 0; par < 2; ++par) {
            int tt = 2 * p + par;
            asm volatile("s_waitcnt vmcnt(2)" ::: "memory");  // tile tt landed (self)
            __builtin_amdgcn_s_barrier();                     // landed for everyone
            asm volatile("" ::: "memory");                    // no hoist above barrier
            if (tt + 2 < nt) stage(tt + 2, (tt + 2) % 3);
            const char* bb = Bs[tt % 3];
            __builtin_amdgcn_s_setprio(1);
            #pragma unroll
            for (int kk = 0; kk < 4; ++kk) {
                f16x8 bf0 = *(const f16x8*)(bb + ((kk * 2 + hi) * 128 + wn * 64 + l31) * 16);
                f16x8 bf1 = *(const f16x8*)(bb + ((kk * 2 + hi) * 128 + wn * 64 + 32 + l31) * 16);
                f16x8 a0 = h0reg[0][par * 4 + kk] * h1v[0];
                f16x8 a1 = h0reg[1][par * 4 + kk] * h1v[1];
                acc[0][0] = __builtin_amdgcn_mfma_f32_32x32x16_f16(a0, bf0, acc[0][0], 0, 0, 0);
                acc[0][1] = __builtin_amdgcn_mfma_f32_32x32x16_f16(a0, bf1, acc[0][1], 0, 0, 0);
                acc[1][0] = __builtin_amdgcn_mfma_f32_32x32x16_f16(a1, bf0, acc[1][0], 0, 0, 0);
                acc[1][1] = __builtin_amdgcn_mfma_f32_32x32x16_f16(a1, bf1, acc[1][1], 0, 0, 0);
            }
            __builtin_amdgcn_s_setprio(0);
        }
    }

    // ---- correction tail (1-2 tiles) ----
    for (int tt = 64; tt < nt; ++tt) {
        int tile = tile_at(tt);
        if (tt + 1 < nt) asm volatile("s_waitcnt vmcnt(2)" ::: "memory");
        else             asm volatile("s_waitcnt vmcnt(0)" ::: "memory");
        __builtin_amdgcn_s_barrier();
        asm volatile("" ::: "memory");
        if (tt + 2 < nt) stage(tt + 2, (tt + 2) % 3);
        const char* bb = Bs[tt % 3];

        f16x8 af[2][4];
        if (tile < 258) {                       // j-corr: G = h1[c]
            int jb = (tile - 256) * 64;
            #pragma unroll
            for (int fm = 0; fm < 2; ++fm) {
                int row = wm * 64 + fm * 32 + l31;
                #pragma unroll
                for (int kk = 0; kk < 4; ++kk) {
                    f16x8 w;
                    #pragma unroll
                    for (int e = 0; e < 8; ++e)
                        w[e] = h1t[(jb + kk * 16 + hi * 8 + e) * 256 + row];
                    af[fm][kk] = w;
                }
            }
        } else if (tile == 258) {               // i-corr lo: G = h0[c], c<64
            #pragma unroll
            for (int fm = 0; fm < 2; ++fm)
                #pragma unroll
                for (int kk = 0; kk < 4; ++kk) af[fm][kk] = h0reg[fm][kk];
        } else if (tile == 259) {               // i-corr hi
            #pragma unroll
            for (int fm = 0; fm < 2; ++fm)
                #pragma unroll
                for (int kk = 0; kk < 4; ++kk) af[fm][kk] = h0reg[fm][4 + kk];
        } else {                                // tile 260: G = 1 at k_local 0
            f16x8 z = (f16x8)(f16)0.f;
            f16x8 o = z;
            if (hi == 0) o[0] = (f16)1.f;
            #pragma unroll
            for (int fm = 0; fm < 2; ++fm) {
                af[fm][0] = o;
                af[fm][1] = z; af[fm][2] = z; af[fm][3] = z;
            }
        }

        __builtin_amdgcn_s_setprio(1);
        #pragma unroll
        for (int kk = 0; kk < 4; ++kk) {
            f16x8 bf0 = *(const f16x8*)(bb + ((kk * 2 + hi) * 128 + wn * 64 + l31) * 16);
            f16x8 bf1 = *(const f16x8*)(bb + ((kk * 2 + hi) * 128 + wn * 64 + 32 + l31) * 16);
            acc[0][0] = __builtin_amdgcn_mfma_f32_32x32x16_f16(af[0][kk], bf0, acc[0][0], 0, 0, 0);
            acc[0][1] = __builtin_amdgcn_mfma_f32_32x32x16_f16(af[0][kk], bf1, acc[0][1], 0, 0, 0);
            acc[1][0] = __builtin_amdgcn_mfma_f32_32x32x16_f16(af[1][kk], bf0, acc[1][0], 0, 0, 0);
            acc[1][1] = __builtin_amdgcn_mfma_f32_32x32x16_f16(af[1][kk], bf1, acc[1][1], 0, 0, 0);
        }
        __builtin_amdgcn_s_setprio(0);
    }

    // ---- epilogue: C/D 32x32 layout col=lane&31, row=(r&3)+8*(r>>2)+4*hi ----
    float* base = ATOMIC ? dst : dst + (size_t)ks * OUT_ELEMS;
    #pragma unroll
    for (int fm = 0; fm < 2; ++fm)
        #pragma unroll
        for (int fn = 0; fn < 2; ++fn)
            #pragma unroll
            for (int r = 0; r < 16; ++r) {
                int row = b0 + wm * 64 + fm * 32 + (r & 3) + 8 * (r >> 2) + 4 * hi;
                int col = wn * 64 + fn * 32 + l31;
                size_t off = ((size_t)row * NA + a) * OUTD + col;
                if (ATOMIC) unsafeAtomicAdd(&base[off], acc[fm][fn][r]);
                else        base[off] = acc[fm][fn][r];
            }
}

// ---------------------------------------------------------------------------
// Reduce: out = P0 + P1 + P2 + P3 (f32x4 vectorized)
// ---------------------------------------------------------------------------
__global__ __launch_bounds__(256) void reduce_kernel(const float* __restrict__ P,
                                                     float* __restrict__ out) {
    int i = blockIdx.x * 256 + threadIdx.x;     // 524288 vec4 elems
    f32x4 s = ((const f32x4*)P)[i];
    s += ((const f32x4*)(P + OUT_ELEMS))[i];
    s += ((const f32x4*)(P + 2 * (size_t)OUT_ELEMS))[i];
    s += ((const f32x4*)(P + 3 * (size_t)OUT_ELEMS))[i];
    ((f32x4*)out)[i] = s;
}

// ---------------------------------------------------------------------------
// Fallback (ws too small): naive but correct f32 kernel.
// ---------------------------------------------------------------------------
__global__ __launch_bounds__(128) void fallback_kernel(const float* __restrict__ x0,
                                                       const float* __restrict__ x1,
                                                       const float* __restrict__ T,
                                                       float* __restrict__ out) {
    int ba = blockIdx.x;
    int b = ba >> 2, a = ba & 3;
    int o = threadIdx.x;
    const float* h0 = x0 + ((size_t)b * NA + a) * DDIM;
    const float* h1 = x1 + ((size_t)b * NA + a) * DDIM;
    float acc = 0.f;
    for (int i = 0; i < 129; ++i) {
        float h0i = (i < 128) ? h0[i] : 1.f;
        const float* Trow = T + (((size_t)a * 129 + i) * 129) * 128 + o;
        float part = 0.f;
        for (int j = 0; j < 129; ++j) {
            float h1j = (j < 128) ? h1[j] : 1.f;
            part += h1j * Trow[(size_t)j * 128];
        }
        acc += h0i * part;
    }
    out[((size_t)b * NA + a) * OUTD + o] = acc;
}

extern "C" void kernel_launch(void* const* d_in, const int* in_sizes, int n_in,
                              void* d_out, int out_size, void* d_ws, size_t ws_size,
                              hipStream_t stream) {
    const float* x0 = (const float*)d_in[0];
    const float* x1 = (const float*)d_in[1];
    const float* T  = (const float*)d_in[2];
    float* out = (float*)d_out;

    if (ws_size < TB_BYTES) {
        fallback_kernel<<<4096 * NA, 128, 0, stream>>>(x0, x1, T, out);
        return;
    }

    f16* Tb = (f16*)d_ws;
    prep_kernel<<<NA * NTILES, 256, 0, stream>>>(T, Tb);

    if (ws_size >= WS_NEEDED) {
        // partial-store path: no atomics
        float* P = (float*)((char*)d_ws + TB_BYTES);
        gemm_kernel<false><<<256, 512, 0, stream>>>(x0, x1, Tb, P);
        reduce_kernel<<<OUT_ELEMS / 4 / 256, 256, 0, stream>>>(P, out);
    } else {
        // atomic fallback path
        hipMemsetAsync(d_out, 0, (size_t)out_size * sizeof(float), stream);
        gemm_kernel<true><<<256, 512, 0, stream>>>(x0, x1, Tb, out);
    }
}